// Round 10
// baseline (789.850 us; speedup 1.0000x reference)
//
#include <hip/hip_runtime.h>
#include <stdint.h>

constexpr int NB = 32, NS = 64, NT = 64, NV = 32000, NE = 256, NH = 512;
constexpr int RG = 64;          // recurrence workgroups: 2 batch-groups x 32 unit-groups
constexpr int UW = 16;          // units per wg
constexpr int BW = 16;          // batches per wg
constexpr int GRW = 3 * UW;     // 48 gate rows per wg
constexpr int TSTEPS = NS + NT - 1;   // 127

typedef unsigned short u16;
typedef unsigned u32;
typedef unsigned long long u64;
typedef short bf16x8 __attribute__((ext_vector_type(8)));
typedef float f32x4  __attribute__((ext_vector_type(4)));
typedef unsigned u32x4 __attribute__((ext_vector_type(4)));

__device__ inline u16 f2bf(float f){
  unsigned int u = __float_as_uint(f);
  u = u + 0x7FFFu + ((u >> 16) & 1u);
  return (u16)(u >> 16);
}
__device__ inline float bf2f(u16 h){ return __uint_as_float(((unsigned)h) << 16); }

__device__ inline void gload_lds16(const u16* g, u16* l){
  __builtin_amdgcn_global_load_lds((const __attribute__((address_space(1))) void*)g,
                                   (__attribute__((address_space(3))) void*)l, 16, 0, 0);
}

// Conflict-free subtiled LDS layouts.
// W plane: 48 rows x 512 bf16 (49152 B). 16B chunk (r<48, k16<64):
//   byte = (k16>>2)*3072 + (r>>4)*1024 + (((k16&3)<<4)|(r&15))*16
// MFMA A-read collapses to kk*3072 + tile*1024 + lane*16  (linear, 0 conflicts)
__device__ inline int ldsW_off(int r, int k16){
  return (k16 >> 2) * 3072 + ((r >> 4) << 10) + (((((k16 & 3) << 4)) | (r & 15)) << 4);
}
// h plane: 16 rows x 512 bf16 (16384 B). chunk (r<16, k16<64):
//   base = (k16>>2)*1024 + (((k16&3)<<4)|r)*16
// XOR-swizzle (both sides): addr = base ^ (((base>>10)&15)<<4)
//   write quarter (fixed r, varying k16): bits4-7 = r ^ kk -> 16 distinct slots, 0-conflict
//   MFMA B-read: kk*1024 + (lane*16 ^ ((kk&15)<<4)) -> per-quarter bijection, 0-conflict
__device__ inline int ldsH_off(int r, int k16){
  int base = ((k16 >> 2) << 10) + (((((k16 & 3) << 4)) | r) << 4);
  return base ^ (((base >> 10) & 15) << 4);
}

// 8 x 16B coherent loads (bypass L1/L2, read MALL) + single drain.
__device__ inline void load_h128(const u32* p, u32x4 v[8]){
  asm volatile(
    "global_load_dwordx4 %0, %8, off sc0 sc1\n\t"
    "global_load_dwordx4 %1, %8, off offset:16 sc0 sc1\n\t"
    "global_load_dwordx4 %2, %8, off offset:32 sc0 sc1\n\t"
    "global_load_dwordx4 %3, %8, off offset:48 sc0 sc1\n\t"
    "global_load_dwordx4 %4, %8, off offset:64 sc0 sc1\n\t"
    "global_load_dwordx4 %5, %8, off offset:80 sc0 sc1\n\t"
    "global_load_dwordx4 %6, %8, off offset:96 sc0 sc1\n\t"
    "global_load_dwordx4 %7, %8, off offset:112 sc0 sc1\n\t"
    "s_waitcnt vmcnt(0)"
    : "=&v"(v[0]), "=&v"(v[1]), "=&v"(v[2]), "=&v"(v[3]),
      "=&v"(v[4]), "=&v"(v[5]), "=&v"(v[6]), "=&v"(v[7])
    : "v"(p)
    : "memory");
}

// ---------------------------------------------------------------- zero init (out row 0, pads, h slots, flags)
__global__ void zero_init(float* __restrict__ out, u16* __restrict__ xdecpad, u16* __restrict__ hallpad,
                          u32* __restrict__ Hpk, u32* __restrict__ flags){
  int i = blockIdx.x * blockDim.x + threadIdx.x, st = gridDim.x * blockDim.x;
  for (int idx = i; idx < NB * NV; idx += st){
    int b = idx / NV, v = idx - b * NV;
    out[(size_t)b * NT * NV + v] = 0.f;
  }
  for (int idx = i; idx < 32 * NE; idx += st) xdecpad[idx] = 0;
  for (int idx = i; idx < 32 * NH; idx += st) hallpad[idx] = 0;
  for (int idx = i; idx < 2 * NB * NH; idx += st) Hpk[idx] = 0;   // slot0 = h(0) = 0
  for (int idx = i; idx < 1024; idx += st) flags[idx] = 0;
}

// ---------------------------------------------------------------- f32 -> bf16
__global__ void cvt_f32_bf16(const float* __restrict__ in, u16* __restrict__ out, int n4){
  int i = blockIdx.x * blockDim.x + threadIdx.x, st = gridDim.x * blockDim.x;
  for (int idx = i; idx < n4; idx += st){
    float4 v = ((const float4*)in)[idx];
    unsigned lo = (unsigned)f2bf(v.x) | ((unsigned)f2bf(v.y) << 16);
    unsigned hi = (unsigned)f2bf(v.z) | ((unsigned)f2bf(v.w) << 16);
    *(uint2*)(out + (size_t)idx * 4) = make_uint2(lo, hi);
  }
}

// ---------------------------------------------------------------- f32 -> (bf16 hi, bf16 lo)
__global__ void cvt_hilo(const float* __restrict__ in, u16* __restrict__ hi, u16* __restrict__ lo, int n){
  int i = blockIdx.x * blockDim.x + threadIdx.x, st = gridDim.x * blockDim.x;
  for (int idx = i; idx < n; idx += st){
    float w = in[idx];
    u16 h = f2bf(w);
    hi[idx] = h;
    lo[idx] = f2bf(w - bf2f(h));
  }
}

// ---------------------------------------------------------------- embedding gather (rows m = t*NB + b)
__global__ void embed_k(const int* __restrict__ idx, int ld, int tcount,
                        const float* __restrict__ emb, u16* __restrict__ xbf){
  int tid = blockIdx.x * blockDim.x + threadIdx.x;
  int n4 = tcount * NB * (NE / 4);
  if (tid >= n4) return;
  int e4 = tid & (NE/4 - 1);
  int m  = tid >> 6;
  int t = m / NB, b = m % NB;
  int row = idx[b * ld + t];
  float4 v = ((const float4*)(emb + (size_t)row * NE))[e4];
  unsigned lo = (unsigned)f2bf(v.x) | ((unsigned)f2bf(v.y) << 16);
  unsigned hi = (unsigned)f2bf(v.z) | ((unsigned)f2bf(v.w) << 16);
  *(uint2*)(xbf + (size_t)m * NE + e4 * 4) = make_uint2(lo, hi);
}

// ---------------------------------------------------------------- bf16 MFMA GEMM: C = A(MxK) * B(NxK)^T + bias
// 2-phase double-buffered pipeline: stage tile k+1 before computing tile k;
// one barrier per K-step (its compiler-emitted vmcnt(0) drains the stage loads).
// MODE 1: fc scatter  row=t*NB+b -> out[b][t+1][col]
// MODE 2: gi transpose -> C[t][col][b]
template<int KDIM, int MODE>
__global__ __launch_bounds__(256) void gemm_bt(const u16* __restrict__ A,
                                               const u16* __restrict__ Bm,
                                               const float* __restrict__ bias,
                                               float* __restrict__ C,
                                               int Mstore, int Nld)
{
  __shared__ u16 As[2 * 128 * 32];
  __shared__ u16 Bs[2 * 128 * 32];
  const int id = blockIdx.x;
  const int q = gridDim.x >> 3;
  const int wg = (id & 7) * q + (id >> 3);
  const int m0 = (wg & 15) * 128, n0 = (wg >> 4) * 128;
  const int tid  = threadIdx.x;
  const int lane = tid & 63;
  const int w = tid >> 6, wm = w >> 1, wn = w & 1;
  f32x4 acc[4][4] = {};

  const int sr = w * 16 + (lane >> 2);
  const int sc = (lane & 3) * 8;
  const u16* aS = A  + (size_t)(m0 + sr) * KDIM + sc;
  const u16* bS = Bm + (size_t)(n0 + sr) * KDIM + sc;
  u16* asl = As + w * 16 * 32;
  u16* bsl = Bs + w * 16 * 32;

  auto STAGE = [&](int p, int k0){
    u16* ad = asl + p * 4096;
    u16* bd = bsl + p * 4096;
    gload_lds16(aS + k0, ad);
    gload_lds16(aS + (size_t)64 * KDIM + k0, ad + 64 * 32);
    gload_lds16(bS + k0, bd);
    gload_lds16(bS + (size_t)64 * KDIM + k0, bd + 64 * 32);
  };

  constexpr int NK = KDIM / 32;
  STAGE(0, 0);
  __syncthreads();
  for (int t2 = 0; t2 < NK; ++t2){
    if (t2 + 1 < NK) STAGE((t2 + 1) & 1, (t2 + 1) * 32);
    const char* Ab = (const char*)As + (t2 & 1) * 8192;
    const char* Bb = (const char*)Bs + (t2 & 1) * 8192;
    bf16x8 af[4], bfr[4];
    #pragma unroll
    for (int i = 0; i < 4; ++i)
      af[i] = *(const bf16x8*)(Ab + (wm*64 + i*16 + (lane & 15)) * 64 + (lane >> 4) * 16);
    #pragma unroll
    for (int j = 0; j < 4; ++j)
      bfr[j] = *(const bf16x8*)(Bb + (wn*64 + j*16 + (lane & 15)) * 64 + (lane >> 4) * 16);
    #pragma unroll
    for (int i = 0; i < 4; ++i)
      #pragma unroll
      for (int j = 0; j < 4; ++j)
        acc[i][j] = __builtin_amdgcn_mfma_f32_16x16x32_bf16(af[i], bfr[j], acc[i][j], 0, 0, 0);
    __syncthreads();
  }

  #pragma unroll
  for (int i = 0; i < 4; ++i){
    #pragma unroll
    for (int j = 0; j < 4; ++j){
      int col = n0 + wn*64 + j*16 + (lane & 15);
      float bv = bias[col];
      #pragma unroll
      for (int rr = 0; rr < 4; ++rr){
        int row = m0 + wm*64 + i*16 + (lane >> 4) * 4 + rr;
        float val = acc[i][j][rr] + bv;
        int t_ = row >> 5, b_ = row & 31;
        if (MODE == 1){
          if (row < Mstore)
            C[(size_t)b_ * (NT * NV) + (size_t)(t_ + 1) * NV + col] = val;
        } else {
          C[((size_t)t_ * 1536 + col) * 32 + b_] = val;
        }
      }
    }
  }
}

// ---------------------------------------------------------------- persistent GRU recurrence
// 64 wgs = 2 batch-groups (bg) x 32 unit-groups (ug). wg owns 16 units x 16 batches:
// W slice = 48 gate rows (hi+lo, 96KB LDS); stages only its 16 batch rows of h (32KB
// from MALL). Barrier width 32 (own cohort only). h plane XOR-swizzled (0-conflict
// on both stage-write and MFMA-read). Sync: u32 h words + per-wg flags at MALL.
__global__ __launch_bounds__(256) void gru_rec(
    const u16* __restrict__ WhiE, const u16* __restrict__ WloE,
    const u16* __restrict__ WhiD, const u16* __restrict__ WloD,
    const float* __restrict__ bhhE, const float* __restrict__ bhhD,
    const float* __restrict__ giTe, const float* __restrict__ giTd,  // [t][1536][32]
    u32* __restrict__ Hpk,            // [2][NB][NH] u32 = hi | lo<<16
    u32* __restrict__ flags,          // [64] stride 4
    u16* __restrict__ Hall)
{
  extern __shared__ char smem[];
  u16* Whi = (u16*)smem;                    // [48][512] subtiled, 49152 B
  u16* Wlo = Whi + GRW * NH;
  u16* Hhi = Wlo + GRW * NH;                // [16][512] subtiled+swizzled, 16384 B
  u16* Hlo = Hhi + BW * NH;
  float* GH = (float*)(Hlo + BW * NH);      // [48][16]

  const int tid  = threadIdx.x;
  const int lane = tid & 63;
  const int w    = tid >> 6;
  const int bg   = blockIdx.x >> 5;         // batch-group 0..1
  const int ug   = blockIdx.x & 31;         // unit-group 0..31
  const int j0   = ug * UW;
  const int b0   = bg * BW;
  const unsigned myid = blockIdx.x;

  const int gu = tid >> 4, gb2 = tid & 15;  // gate-phase: unit-local, batch-local
  const int jg = j0 + gu;
  const int bglob = b0 + gb2;
  const float beR = bhhE[jg], beZ = bhhE[NH + jg], beN = bhhE[2*NH + jg];
  const float bdR = bhhD[jg], bdZ = bhhD[NH + jg], bdN = bhhD[2*NH + jg];

  auto stageW = [&](const u16* Hi, const u16* Lo){
    for (int c = tid; c < GRW * 64; c += 256){   // 3072 16B chunks
      int r = c >> 6, k16 = c & 63;
      int grow = (r >> 4) * NH + j0 + (r & 15);  // gate*512 + unit
      int d = ldsW_off(r, k16);
      *(uint4*)((char*)Whi + d) = *(const uint4*)(Hi + (size_t)grow * NH + k16 * 8);
      *(uint4*)((char*)Wlo + d) = *(const uint4*)(Lo + (size_t)grow * NH + k16 * 8);
    }
  };
  stageW(WhiE, WloE);

  const int srl = tid >> 4;            // staging local row 0..15
  const int sqq = tid & 15;            // 128B segment within row

  for (int t = 0; t < TSTEPS; ++t){
    const bool dec = (t >= NS);
    __syncthreads();                   // drains publish stores; planes free for restage
    if (tid == 0 && t > 0)
      __hip_atomic_store(&flags[myid * 4], (u32)t, __ATOMIC_RELAXED, __HIP_MEMORY_SCOPE_AGENT);
    if (t == NS) stageW(WhiD, WloD);

    // ---- poll: own cohort's 32 flags only; lane l watches wg bg*32+(l&31); own wg skipped
    {
      int spins = 0;
      const int fl = (bg << 5) + (lane & 31);
      while (true){
        u32 f = __hip_atomic_load(&flags[fl * 4], __ATOMIC_RELAXED, __HIP_MEMORY_SCOPE_AGENT);
        if (__all((int)(lane >= 32 || (lane & 31) == ug || f >= (u32)t))) break;
        __builtin_amdgcn_s_sleep(1);
        if (++spins > (1 << 18)) break;   // failsafe: wrong answer, not hang
      }
    }

    // ---- stage h(t) rows b0..b0+15 from Hpk[t&1]: 8 x 16B coherent loads per thread
    {
      const u32* Hq = Hpk + (size_t)(t & 1) * NB * NH;
      u32x4 v[8];
      load_h128(Hq + (size_t)(b0 + srl) * NH + sqq * 32, v);
      #pragma unroll
      for (int i = 0; i < 4; ++i){
        u32x4 a = v[2*i], b2 = v[2*i+1];
        uint4 hw = make_uint4((a[0] & 0xffffu) | (a[1] << 16), (a[2] & 0xffffu) | (a[3] << 16),
                              (b2[0] & 0xffffu) | (b2[1] << 16), (b2[2] & 0xffffu) | (b2[3] << 16));
        uint4 lw = make_uint4((a[0] >> 16) | (a[1] & 0xffff0000u), (a[2] >> 16) | (a[3] & 0xffff0000u),
                              (b2[0] >> 16) | (b2[1] & 0xffff0000u), (b2[2] >> 16) | (b2[3] & 0xffff0000u));
        int d = ldsH_off(srl, sqq * 4 + i);
        *(uint4*)((char*)Hhi + d) = hw;
        *(uint4*)((char*)Hlo + d) = lw;
      }
    }
    __syncthreads();

    // ---- gi loads early (coalesced [t][gate*512+j][b]); consumed after MFMA
    const float* gT = dec ? (giTd + (size_t)(t - NS) * 1536 * 32)
                          : (giTe + (size_t)t * 1536 * 32);
    float gr = gT[(size_t)(0 * NH + jg) * 32 + bglob];
    float gz = gT[(size_t)(1 * NH + jg) * 32 + bglob];
    float gn = gT[(size_t)(2 * NH + jg) * 32 + bglob];

    // ---- gh = W_slice(48x512) . h(16x512)^T ; waves 0-2 own one 16-row tile each
    if (w < 3){
      f32x4 acc0 = {0.f,0.f,0.f,0.f}, acc1 = {0.f,0.f,0.f,0.f};
      const int ab = w * 1024 + lane * 16;
      const int bb = lane * 16;
      #pragma unroll
      for (int kk = 0; kk < 16; kk += 2){
        const int bx0 = kk * 1024 + (bb ^ ((kk & 15) << 4));
        const int bx1 = (kk+1) * 1024 + (bb ^ (((kk+1) & 15) << 4));
        bf16x8 ah0 = *(const bf16x8*)((const char*)Whi + kk * 3072 + ab);
        bf16x8 al0 = *(const bf16x8*)((const char*)Wlo + kk * 3072 + ab);
        bf16x8 bh0 = *(const bf16x8*)((const char*)Hhi + bx0);
        bf16x8 bl0 = *(const bf16x8*)((const char*)Hlo + bx0);
        acc0 = __builtin_amdgcn_mfma_f32_16x16x32_bf16(ah0, bh0, acc0, 0, 0, 0);
        acc0 = __builtin_amdgcn_mfma_f32_16x16x32_bf16(al0, bh0, acc0, 0, 0, 0);
        acc0 = __builtin_amdgcn_mfma_f32_16x16x32_bf16(ah0, bl0, acc0, 0, 0, 0);
        bf16x8 ah1 = *(const bf16x8*)((const char*)Whi + (kk+1) * 3072 + ab);
        bf16x8 al1 = *(const bf16x8*)((const char*)Wlo + (kk+1) * 3072 + ab);
        bf16x8 bh1 = *(const bf16x8*)((const char*)Hhi + bx1);
        bf16x8 bl1 = *(const bf16x8*)((const char*)Hlo + bx1);
        acc1 = __builtin_amdgcn_mfma_f32_16x16x32_bf16(ah1, bh1, acc1, 0, 0, 0);
        acc1 = __builtin_amdgcn_mfma_f32_16x16x32_bf16(al1, bh1, acc1, 0, 0, 0);
        acc1 = __builtin_amdgcn_mfma_f32_16x16x32_bf16(ah1, bl1, acc1, 0, 0, 0);
      }
      f32x4 accs = acc0 + acc1;
      int col = lane & 15;
      #pragma unroll
      for (int r2 = 0; r2 < 4; ++r2){
        int row = w * 16 + ((lane >> 4) << 2) + r2;
        GH[row * BW + col] = accs[r2];
      }
    }
    __syncthreads();

    // ---- gate math (one (unit, batch) per thread); publish h(t+1) u32 agent atomic
    {
      float ghr = GH[(0 * UW + gu) * BW + gb2] + (dec ? bdR : beR);
      float ghz = GH[(1 * UW + gu) * BW + gb2] + (dec ? bdZ : beZ);
      float ghn = GH[(2 * UW + gu) * BW + gb2] + (dec ? bdN : beN);
      float r = 1.f / (1.f + expf(-(gr + ghr)));
      float z = 1.f / (1.f + expf(-(gz + ghz)));
      float n = tanhf(gn + r * ghn);
      int coff = ldsH_off(gb2, jg >> 3) + (jg & 7) * 2;
      float hp = bf2f(*(const u16*)((char*)Hhi + coff))
               + bf2f(*(const u16*)((char*)Hlo + coff));
      float hnew = (1.f - z) * n + z * hp;
      u16 hi = f2bf(hnew);
      u16 lo = f2bf(hnew - bf2f(hi));
      if (dec) Hall[((size_t)(t - NS) * NB + bglob) * NH + jg] = hi;
      if (t < TSTEPS - 1){
        __hip_atomic_store(&Hpk[((size_t)((t + 1) & 1) * NB + bglob) * NH + jg],
                           (u32)hi | ((u32)lo << 16),
                           __ATOMIC_RELAXED, __HIP_MEMORY_SCOPE_AGENT);
      }
    }
  }
}

// ---------------------------------------------------------------- launcher
extern "C" void kernel_launch(void* const* d_in, const int* in_sizes, int n_in,
                              void* d_out, int out_size, void* d_ws, size_t ws_size,
                              hipStream_t stream)
{
  const int*   src      = (const int*)  d_in[0];
  const int*   trg      = (const int*)  d_in[1];
  const float* emb_enc  = (const float*)d_in[2];
  const float* W_ih_enc = (const float*)d_in[3];
  const float* W_hh_enc = (const float*)d_in[4];
  const float* b_ih_enc = (const float*)d_in[5];
  const float* b_hh_enc = (const float*)d_in[6];
  const float* emb_dec  = (const float*)d_in[7];
  const float* W_ih_dec = (const float*)d_in[8];
  const float* W_hh_dec = (const float*)d_in[9];
  const float* b_ih_dec = (const float*)d_in[10];
  const float* b_hh_dec = (const float*)d_in[11];
  const float* fc_W     = (const float*)d_in[12];
  const float* fc_b     = (const float*)d_in[13];
  float* out = (float*)d_out;

  char* ws = (char*)d_ws;
  size_t o = 0;
  auto alloc = [&](size_t bytes){ size_t r = o; o += (bytes + 255) & ~(size_t)255; return r; };
  u16*   xenc  = (u16*)(ws + alloc((size_t)2048 * NE * 2));
  u16*   xdec  = (u16*)(ws + alloc((size_t)2048 * NE * 2));   // 2016 used + 32 pad
  u16*   wihe  = (u16*)(ws + alloc((size_t)3 * NH * NE * 2));
  u16*   wihd  = (u16*)(ws + alloc((size_t)3 * NH * NE * 2));
  u16*   fcWbf = (u16*)(ws + alloc((size_t)NV * NH * 2));
  u16*   whiE  = (u16*)(ws + alloc((size_t)3 * NH * NH * 2));
  u16*   wloE  = (u16*)(ws + alloc((size_t)3 * NH * NH * 2));
  u16*   whiD  = (u16*)(ws + alloc((size_t)3 * NH * NH * 2));
  u16*   wloD  = (u16*)(ws + alloc((size_t)3 * NH * NH * 2));
  float* gie   = (float*)(ws + alloc((size_t)2048 * 3 * NH * 4));   // giT [t][1536][32]
  float* gid   = (float*)(ws + alloc((size_t)2048 * 3 * NH * 4));
  u32*   Hpk   = (u32*)(ws + alloc((size_t)2 * NB * NH * 4));
  u32*   flags = (u32*)(ws + alloc(4096));
  u16*   Hall  = (u16*)(ws + alloc((size_t)2048 * NH * 2));   // 2016 used + 32 pad

  zero_init<<<256, 256, 0, stream>>>(out, xdec + (size_t)2016 * NE, Hall + (size_t)2016 * NH, Hpk, flags);
  cvt_f32_bf16<<<384, 256, 0, stream>>>(W_ih_enc, wihe, 3*NH*NE/4);
  cvt_f32_bf16<<<384, 256, 0, stream>>>(W_ih_dec, wihd, 3*NH*NE/4);
  cvt_f32_bf16<<<2048, 256, 0, stream>>>(fc_W, fcWbf, NV*NH/4);
  cvt_hilo<<<1024, 256, 0, stream>>>(W_hh_enc, whiE, wloE, 3*NH*NH);
  cvt_hilo<<<1024, 256, 0, stream>>>(W_hh_dec, whiD, wloD, 3*NH*NH);
  embed_k<<<(NS*NB*64 + 255)/256, 256, 0, stream>>>(src, NS, NS, emb_enc, xenc);
  embed_k<<<((NT-1)*NB*64 + 255)/256, 256, 0, stream>>>(trg, NT, NT-1, emb_dec, xdec);

  // gi = x @ W_ih^T + b_ih -> transposed [t][1536][32]
  gemm_bt<NE, 2><<<192, 256, 0, stream>>>(xenc, wihe, b_ih_enc, gie, 2048, 0);
  gemm_bt<NE, 2><<<192, 256, 0, stream>>>(xdec, wihd, b_ih_dec, gid, 2048, 0);

  // persistent recurrence
  // LDS: W hi+lo 2*49152 + h hi+lo 2*16384 + GH 48*16*4 = 134144
  constexpr int SMEM_BYTES = 2 * (GRW * NH * 2) + 2 * (BW * NH * 2) + GRW * BW * 4;
  static_assert(SMEM_BYTES <= 160 * 1024, "LDS over 160 KiB");
  static_assert(SMEM_BYTES == 134144, "unexpected LDS size");
  (void)hipFuncSetAttribute(reinterpret_cast<const void*>(&gru_rec),
                            hipFuncAttributeMaxDynamicSharedMemorySize, SMEM_BYTES);
  gru_rec<<<RG, 256, SMEM_BYTES, stream>>>(whiE, wloE, whiD, wloD, b_hh_enc, b_hh_dec,
                                           gie, gid, Hpk, flags, Hall);

  // logits = h2 @ fc_W^T + fc_b  (M=2048 pad, N=32000, K=512) -> grid 250*16 = 4000
  gemm_bt<NH, 1><<<4000, 256, 0, stream>>>(Hall, fcWbf, fc_b, out, 2016, 0);
}

// Round 11
// 625.957 us; speedup vs baseline: 1.2618x; 1.2618x over previous
//
#include <hip/hip_runtime.h>
#include <stdint.h>

constexpr int NB = 32, NS = 64, NT = 64, NV = 32000, NE = 256, NH = 512;
constexpr int RG = 64;          // recurrence wgs: 2 batch-groups x 32 unit-groups
constexpr int UW = 16;          // units per wg
constexpr int BW = 16;          // batches per wg
constexpr int GRW = 3 * UW;     // 48 gate rows per wg
constexpr int TSTEPS = NS + NT - 1;   // 127

typedef unsigned short u16;
typedef unsigned u32;
typedef short bf16x8 __attribute__((ext_vector_type(8)));
typedef float f32x4  __attribute__((ext_vector_type(4)));
typedef unsigned u32x4 __attribute__((ext_vector_type(4)));

__device__ inline u16 f2bf(float f){
  unsigned int u = __float_as_uint(f);
  u = u + 0x7FFFu + ((u >> 16) & 1u);
  return (u16)(u >> 16);
}
__device__ inline float bf2f(u16 h){ return __uint_as_float(((unsigned)h) << 16); }

__device__ inline void gload_lds16(const u16* g, u16* l){
  __builtin_amdgcn_global_load_lds((const __attribute__((address_space(1))) void*)g,
                                   (__attribute__((address_space(3))) void*)l, 16, 0, 0);
}

// W plane: 48 rows x 512 bf16. 16B chunk (r<48, k16<64):
//   byte = (k16>>2)*3072 + (r>>4)*1024 + (((k16&3)<<4)|(r&15))*16
__device__ inline int ldsW_off(int r, int k16){
  return (k16 >> 2) * 3072 + ((r >> 4) << 10) + (((((k16 & 3) << 4)) | (r & 15)) << 4);
}
// h plane: 16 rows x 512 bf16, XOR-swizzled (r10-verified: 0-conflict on write+MFMA read)
__device__ inline int ldsH_off(int r, int k16){
  int base = ((k16 >> 2) << 10) + (((((k16 & 3) << 4)) | r) << 4);
  return base ^ (((base >> 10) & 15) << 4);
}

// ---------------------------------------------------------------- zero init
__global__ void zero_init(float* __restrict__ out, u16* __restrict__ xdecpad, u16* __restrict__ hallpad,
                          u32* __restrict__ Hpk, u32* __restrict__ flags){
  int i = blockIdx.x * blockDim.x + threadIdx.x, st = gridDim.x * blockDim.x;
  for (int idx = i; idx < NB * NV; idx += st){
    int b = idx / NV, v = idx - b * NV;
    out[(size_t)b * NT * NV + v] = 0.f;
  }
  for (int idx = i; idx < 32 * NE; idx += st) xdecpad[idx] = 0;
  for (int idx = i; idx < 32 * NH; idx += st) hallpad[idx] = 0;
  for (int idx = i; idx < 2 * 2 * 32 * 256; idx += st) Hpk[idx] = 0;  // slot0 = h(0) = 0
  for (int idx = i; idx < 1024; idx += st) flags[idx] = 0;
}

// ---------------------------------------------------------------- f32 -> bf16
__global__ void cvt_f32_bf16(const float* __restrict__ in, u16* __restrict__ out, int n4){
  int i = blockIdx.x * blockDim.x + threadIdx.x, st = gridDim.x * blockDim.x;
  for (int idx = i; idx < n4; idx += st){
    float4 v = ((const float4*)in)[idx];
    unsigned lo = (unsigned)f2bf(v.x) | ((unsigned)f2bf(v.y) << 16);
    unsigned hi = (unsigned)f2bf(v.z) | ((unsigned)f2bf(v.w) << 16);
    *(uint2*)(out + (size_t)idx * 4) = make_uint2(lo, hi);
  }
}

// ---------------------------------------------------------------- f32 -> (bf16 hi, bf16 lo)
__global__ void cvt_hilo(const float* __restrict__ in, u16* __restrict__ hi, u16* __restrict__ lo, int n){
  int i = blockIdx.x * blockDim.x + threadIdx.x, st = gridDim.x * blockDim.x;
  for (int idx = i; idx < n; idx += st){
    float w = in[idx];
    u16 h = f2bf(w);
    hi[idx] = h;
    lo[idx] = f2bf(w - bf2f(h));
  }
}

// ---------------------------------------------------------------- embedding gather (rows m = t*NB + b)
__global__ void embed_k(const int* __restrict__ idx, int ld, int tcount,
                        const float* __restrict__ emb, u16* __restrict__ xbf){
  int tid = blockIdx.x * blockDim.x + threadIdx.x;
  int n4 = tcount * NB * (NE / 4);
  if (tid >= n4) return;
  int e4 = tid & (NE/4 - 1);
  int m  = tid >> 6;
  int t = m / NB, b = m % NB;
  int row = idx[b * ld + t];
  float4 v = ((const float4*)(emb + (size_t)row * NE))[e4];
  unsigned lo = (unsigned)f2bf(v.x) | ((unsigned)f2bf(v.y) << 16);
  unsigned hi = (unsigned)f2bf(v.z) | ((unsigned)f2bf(v.w) << 16);
  *(uint2*)(xbf + (size_t)m * NE + e4 * 4) = make_uint2(lo, hi);
}

// ---------------------------------------------------------------- bf16 MFMA GEMM: C = A(MxK) * B(NxK)^T + bias
// 2-phase double-buffered. MODE 0: plain C[row*Nld+col]. MODE 1: fc scatter -> out[b][t+1][col].
template<int KDIM, int MODE>
__global__ __launch_bounds__(256) void gemm_bt(const u16* __restrict__ A,
                                               const u16* __restrict__ Bm,
                                               const float* __restrict__ bias,
                                               float* __restrict__ C,
                                               int Mstore, int Nld)
{
  __shared__ u16 As[2 * 128 * 32];
  __shared__ u16 Bs[2 * 128 * 32];
  const int id = blockIdx.x;
  const int q = gridDim.x >> 3;
  const int wg = (id & 7) * q + (id >> 3);
  const int m0 = (wg & 15) * 128, n0 = (wg >> 4) * 128;
  const int tid  = threadIdx.x;
  const int lane = tid & 63;
  const int w = tid >> 6, wm = w >> 1, wn = w & 1;
  f32x4 acc[4][4] = {};

  const int sr = w * 16 + (lane >> 2);
  const int sc = (lane & 3) * 8;
  const u16* aS = A  + (size_t)(m0 + sr) * KDIM + sc;
  const u16* bS = Bm + (size_t)(n0 + sr) * KDIM + sc;
  u16* asl = As + w * 16 * 32;
  u16* bsl = Bs + w * 16 * 32;

  auto STAGE = [&](int p, int k0){
    u16* ad = asl + p * 4096;
    u16* bd = bsl + p * 4096;
    gload_lds16(aS + k0, ad);
    gload_lds16(aS + (size_t)64 * KDIM + k0, ad + 64 * 32);
    gload_lds16(bS + k0, bd);
    gload_lds16(bS + (size_t)64 * KDIM + k0, bd + 64 * 32);
  };

  constexpr int NK = KDIM / 32;
  STAGE(0, 0);
  __syncthreads();
  for (int t2 = 0; t2 < NK; ++t2){
    if (t2 + 1 < NK) STAGE((t2 + 1) & 1, (t2 + 1) * 32);
    const char* Ab = (const char*)As + (t2 & 1) * 8192;
    const char* Bb = (const char*)Bs + (t2 & 1) * 8192;
    bf16x8 af[4], bfr[4];
    #pragma unroll
    for (int i = 0; i < 4; ++i)
      af[i] = *(const bf16x8*)(Ab + (wm*64 + i*16 + (lane & 15)) * 64 + (lane >> 4) * 16);
    #pragma unroll
    for (int j = 0; j < 4; ++j)
      bfr[j] = *(const bf16x8*)(Bb + (wn*64 + j*16 + (lane & 15)) * 64 + (lane >> 4) * 16);
    #pragma unroll
    for (int i = 0; i < 4; ++i)
      #pragma unroll
      for (int j = 0; j < 4; ++j)
        acc[i][j] = __builtin_amdgcn_mfma_f32_16x16x32_bf16(af[i], bfr[j], acc[i][j], 0, 0, 0);
    __syncthreads();
  }

  #pragma unroll
  for (int i = 0; i < 4; ++i){
    #pragma unroll
    for (int j = 0; j < 4; ++j){
      int col = n0 + wn*64 + j*16 + (lane & 15);
      float bv = bias[col];
      #pragma unroll
      for (int rr = 0; rr < 4; ++rr){
        int row = m0 + wm*64 + i*16 + (lane >> 4) * 4 + rr;
        float val = acc[i][j][rr] + bv;
        if (MODE == 1){
          if (row < Mstore){
            int t_ = row >> 5, b_ = row & 31;
            C[(size_t)b_ * (NT * NV) + (size_t)(t_ + 1) * NV + col] = val;
          }
        } else {
          C[(size_t)row * Nld + col] = val;
        }
      }
    }
  }
}

// ---------------------------------------------------------------- persistent GRU recurrence
// 64 wgs = 2 batch-groups x 32 unit-groups; wg owns 16 units x 16 batches.
// h exchange via 1KB producer blocks Hpk[slot][bg][ug][b_local][u] (u32 = hi|lo<<16).
// FINE-GRAINED PULL: wave w polls its 8 producers' flags and issues each ready
// producer's block load immediately (16B/lane asm, no wait); one vmcnt(0)+sched_barrier
// before unpack. Own block always-ready. Union of 4 waves covers all 32 flags >= t
// before publish into the recycled slot (slot-parity double buffer, r5 invariant).
__global__ __launch_bounds__(256) void gru_rec(
    const u16* __restrict__ WhiE, const u16* __restrict__ WloE,
    const u16* __restrict__ WhiD, const u16* __restrict__ WloD,
    const float* __restrict__ bhhE, const float* __restrict__ bhhD,
    const float* __restrict__ gie, const float* __restrict__ gid,  // [t][b][1536]
    u32* __restrict__ Hpk,            // [2][2][32][16][16] u32
    u32* __restrict__ flags,          // [64] stride 4
    u16* __restrict__ Hall)
{
  extern __shared__ char smem[];
  u16* Whi = (u16*)smem;                    // [48][512] subtiled, 49152 B
  u16* Wlo = Whi + GRW * NH;
  u16* Hhi = Wlo + GRW * NH;                // [16][512] subtiled+swizzled, 16384 B
  u16* Hlo = Hhi + BW * NH;
  float* GH = (float*)(Hlo + BW * NH);      // [48][17] padded

  const int tid  = threadIdx.x;
  const int lane = tid & 63;
  const int w    = tid >> 6;
  const int bg   = blockIdx.x >> 5;         // batch-group 0..1
  const int ug   = blockIdx.x & 31;         // unit-group 0..31
  const int j0   = ug * UW;
  const int b0   = bg * BW;
  const unsigned myid = blockIdx.x;

  // gate-phase mapping: unit fastest (publish 256B-contiguous per wave, gi coalesced)
  const int gu = tid & 15, gb2 = tid >> 4;
  const int jg = j0 + gu;
  const int bglob = b0 + gb2;
  const float beR = bhhE[jg], beZ = bhhE[NH + jg], beN = bhhE[2*NH + jg];
  const float bdR = bhhD[jg], bdZ = bhhD[NH + jg], bdN = bhhD[2*NH + jg];

  auto stageW = [&](const u16* Hi, const u16* Lo){
    for (int c = tid; c < GRW * 64; c += 256){
      int r = c >> 6, k16 = c & 63;
      int grow = (r >> 4) * NH + j0 + (r & 15);
      int d = ldsW_off(r, k16);
      *(uint4*)((char*)Whi + d) = *(const uint4*)(Hi + (size_t)grow * NH + k16 * 8);
      *(uint4*)((char*)Wlo + d) = *(const uint4*)(Lo + (size_t)grow * NH + k16 * 8);
    }
  };
  stageW(WhiE, WloE);

  for (int t = 0; t < TSTEPS; ++t){
    const bool dec = (t >= NS);
    __syncthreads();                   // drains publish stores (MALL-acked)
    if (tid == 0 && t > 0)
      __hip_atomic_store(&flags[myid * 4], (u32)t, __ATOMIC_RELAXED, __HIP_MEMORY_SCOPE_AGENT);
    if (t == NS) stageW(WhiD, WloD);

    // ---- fine-grained pull of 32 producer blocks (wave w owns producers w*8..w*8+7)
    {
      const u32* Hq = Hpk + (size_t)((t & 1) * 2 + bg) * 8192;
      u32x4 v[8] = {};
      unsigned have = 0;
      int spins = 0;
      const int fb = (bg << 5) + (w << 3);
      while (have != 0xffu){
        u32 f = __hip_atomic_load(&flags[(fb + (lane & 7)) * 4], __ATOMIC_RELAXED, __HIP_MEMORY_SCOPE_AGENT);
        bool rl = (lane < 8) && ((w * 8 + lane == ug) || f >= (u32)t);
        unsigned rdy = (unsigned)__ballot((int)rl) & 0xffu;
        unsigned newly = rdy & ~have;
        if (newly){
          #pragma unroll
          for (int p = 0; p < 8; ++p){
            if (newly & (1u << p)){
              const u32* src = Hq + ((w * 8 + p) << 8) + lane * 4;
              asm volatile("global_load_dwordx4 %0, %1, off sc0 sc1"
                           : "=v"(v[p]) : "v"(src) : "memory");
            }
          }
          have |= newly;
        }
        if (have != 0xffu){
          __builtin_amdgcn_s_sleep(1);
          if (++spins > (1 << 18)) break;   // failsafe: wrong answer, not hang
        }
      }
      asm volatile("s_waitcnt vmcnt(0)" ::: "memory");
      __builtin_amdgcn_sched_barrier(0);
      const int prow = lane >> 2, pq = lane & 3;
      #pragma unroll
      for (int p = 0; p < 8; ++p){
        u32 a0 = v[p][0], a1 = v[p][1], a2 = v[p][2], a3 = v[p][3];
        uint2 hw = make_uint2((a0 & 0xffffu) | (a1 << 16), (a2 & 0xffffu) | (a3 << 16));
        uint2 lw = make_uint2((a0 >> 16) | (a1 & 0xffff0000u), (a2 >> 16) | (a3 & 0xffff0000u));
        int k16 = (w * 8 + p) * 2 + (pq >> 1);
        int d = ldsH_off(prow, k16) + (pq & 1) * 8;
        *(uint2*)((char*)Hhi + d) = hw;
        *(uint2*)((char*)Hlo + d) = lw;
      }
    }
    __syncthreads();

    // ---- gi loads early (plain [t][b][1536], unit-fastest -> coalesced)
    const float* gp = (dec ? (gid + ((size_t)(t - NS) * NB + bglob) * 1536)
                           : (gie + ((size_t)t * NB + bglob) * 1536));
    float gr = gp[jg], gz = gp[NH + jg], gn = gp[2 * NH + jg];

    // ---- gh = W_slice(48x512) . h(16x512)^T ; waves 0-2 own one 16-row tile each
    if (w < 3){
      f32x4 acc0 = {0.f,0.f,0.f,0.f}, acc1 = {0.f,0.f,0.f,0.f};
      const int ab = w * 1024 + lane * 16;
      const int bb = lane * 16;
      #pragma unroll
      for (int kk = 0; kk < 16; kk += 2){
        const int bx0 = kk * 1024 + (bb ^ ((kk & 15) << 4));
        const int bx1 = (kk+1) * 1024 + (bb ^ (((kk+1) & 15) << 4));
        bf16x8 ah0 = *(const bf16x8*)((const char*)Whi + kk * 3072 + ab);
        bf16x8 al0 = *(const bf16x8*)((const char*)Wlo + kk * 3072 + ab);
        bf16x8 bh0 = *(const bf16x8*)((const char*)Hhi + bx0);
        bf16x8 bl0 = *(const bf16x8*)((const char*)Hlo + bx0);
        acc0 = __builtin_amdgcn_mfma_f32_16x16x32_bf16(ah0, bh0, acc0, 0, 0, 0);
        acc0 = __builtin_amdgcn_mfma_f32_16x16x32_bf16(al0, bh0, acc0, 0, 0, 0);
        acc0 = __builtin_amdgcn_mfma_f32_16x16x32_bf16(ah0, bl0, acc0, 0, 0, 0);
        bf16x8 ah1 = *(const bf16x8*)((const char*)Whi + (kk+1) * 3072 + ab);
        bf16x8 al1 = *(const bf16x8*)((const char*)Wlo + (kk+1) * 3072 + ab);
        bf16x8 bh1 = *(const bf16x8*)((const char*)Hhi + bx1);
        bf16x8 bl1 = *(const bf16x8*)((const char*)Hlo + bx1);
        acc1 = __builtin_amdgcn_mfma_f32_16x16x32_bf16(ah1, bh1, acc1, 0, 0, 0);
        acc1 = __builtin_amdgcn_mfma_f32_16x16x32_bf16(al1, bh1, acc1, 0, 0, 0);
        acc1 = __builtin_amdgcn_mfma_f32_16x16x32_bf16(ah1, bl1, acc1, 0, 0, 0);
      }
      f32x4 accs = acc0 + acc1;
      int col = lane & 15;
      #pragma unroll
      for (int r2 = 0; r2 < 4; ++r2){
        int row = w * 16 + ((lane >> 4) << 2) + r2;
        GH[row * 17 + col] = accs[r2];
      }
    }
    __syncthreads();

    // ---- gate math (unit gu, batch gb2); publish h(t+1) into producer block
    {
      float ghr = GH[(0 * UW + gu) * 17 + gb2] + (dec ? bdR : beR);
      float ghz = GH[(1 * UW + gu) * 17 + gb2] + (dec ? bdZ : beZ);
      float ghn = GH[(2 * UW + gu) * 17 + gb2] + (dec ? bdN : beN);
      float r = 1.f / (1.f + expf(-(gr + ghr)));
      float z = 1.f / (1.f + expf(-(gz + ghz)));
      float n = tanhf(gn + r * ghn);
      int coff = ldsH_off(gb2, jg >> 3) + (jg & 7) * 2;
      float hp = bf2f(*(const u16*)((char*)Hhi + coff))
               + bf2f(*(const u16*)((char*)Hlo + coff));
      float hnew = (1.f - z) * n + z * hp;
      u16 hi = f2bf(hnew);
      u16 lo = f2bf(hnew - bf2f(hi));
      if (dec) Hall[((size_t)(t - NS) * NB + bglob) * NH + jg] = hi;
      if (t < TSTEPS - 1){
        u32* dst = Hpk + (size_t)((((t + 1) & 1) * 2 + bg) * 32 + ug) * 256 + gb2 * 16 + gu;
        __hip_atomic_store(dst, (u32)hi | ((u32)lo << 16),
                           __ATOMIC_RELAXED, __HIP_MEMORY_SCOPE_AGENT);
      }
    }
  }
}

// ---------------------------------------------------------------- launcher
extern "C" void kernel_launch(void* const* d_in, const int* in_sizes, int n_in,
                              void* d_out, int out_size, void* d_ws, size_t ws_size,
                              hipStream_t stream)
{
  const int*   src      = (const int*)  d_in[0];
  const int*   trg      = (const int*)  d_in[1];
  const float* emb_enc  = (const float*)d_in[2];
  const float* W_ih_enc = (const float*)d_in[3];
  const float* W_hh_enc = (const float*)d_in[4];
  const float* b_ih_enc = (const float*)d_in[5];
  const float* b_hh_enc = (const float*)d_in[6];
  const float* emb_dec  = (const float*)d_in[7];
  const float* W_ih_dec = (const float*)d_in[8];
  const float* W_hh_dec = (const float*)d_in[9];
  const float* b_ih_dec = (const float*)d_in[10];
  const float* b_hh_dec = (const float*)d_in[11];
  const float* fc_W     = (const float*)d_in[12];
  const float* fc_b     = (const float*)d_in[13];
  float* out = (float*)d_out;

  char* ws = (char*)d_ws;
  size_t o = 0;
  auto alloc = [&](size_t bytes){ size_t r = o; o += (bytes + 255) & ~(size_t)255; return r; };
  u16*   xenc  = (u16*)(ws + alloc((size_t)2048 * NE * 2));
  u16*   xdec  = (u16*)(ws + alloc((size_t)2048 * NE * 2));   // 2016 used + 32 pad
  u16*   wihe  = (u16*)(ws + alloc((size_t)3 * NH * NE * 2));
  u16*   wihd  = (u16*)(ws + alloc((size_t)3 * NH * NE * 2));
  u16*   fcWbf = (u16*)(ws + alloc((size_t)NV * NH * 2));
  u16*   whiE  = (u16*)(ws + alloc((size_t)3 * NH * NH * 2));
  u16*   wloE  = (u16*)(ws + alloc((size_t)3 * NH * NH * 2));
  u16*   whiD  = (u16*)(ws + alloc((size_t)3 * NH * NH * 2));
  u16*   wloD  = (u16*)(ws + alloc((size_t)3 * NH * NH * 2));
  float* gie   = (float*)(ws + alloc((size_t)2048 * 3 * NH * 4));   // [t][b][1536]
  float* gid   = (float*)(ws + alloc((size_t)2048 * 3 * NH * 4));
  u32*   Hpk   = (u32*)(ws + alloc((size_t)2 * 2 * 32 * 256 * 4)); // producer blocks
  u32*   flags = (u32*)(ws + alloc(4096));
  u16*   Hall  = (u16*)(ws + alloc((size_t)2048 * NH * 2));   // 2016 used + 32 pad

  zero_init<<<256, 256, 0, stream>>>(out, xdec + (size_t)2016 * NE, Hall + (size_t)2016 * NH, Hpk, flags);
  cvt_f32_bf16<<<384, 256, 0, stream>>>(W_ih_enc, wihe, 3*NH*NE/4);
  cvt_f32_bf16<<<384, 256, 0, stream>>>(W_ih_dec, wihd, 3*NH*NE/4);
  cvt_f32_bf16<<<2048, 256, 0, stream>>>(fc_W, fcWbf, NV*NH/4);
  cvt_hilo<<<1024, 256, 0, stream>>>(W_hh_enc, whiE, wloE, 3*NH*NH);
  cvt_hilo<<<1024, 256, 0, stream>>>(W_hh_dec, whiD, wloD, 3*NH*NH);
  embed_k<<<(NS*NB*64 + 255)/256, 256, 0, stream>>>(src, NS, NS, emb_enc, xenc);
  embed_k<<<((NT-1)*NB*64 + 255)/256, 256, 0, stream>>>(trg, NT, NT-1, emb_dec, xdec);

  // gi = x @ W_ih^T + b_ih  -> plain [t][b][1536]
  gemm_bt<NE, 0><<<192, 256, 0, stream>>>(xenc, wihe, b_ih_enc, gie, 2048, 3*NH);
  gemm_bt<NE, 0><<<192, 256, 0, stream>>>(xdec, wihd, b_ih_dec, gid, 2048, 3*NH);

  // persistent recurrence
  // LDS: W hi+lo 2*49152 + h hi+lo 2*16384 + GH 48*17*4 = 134336
  constexpr int SMEM_BYTES = 2 * (GRW * NH * 2) + 2 * (BW * NH * 2) + GRW * 17 * 4;
  static_assert(SMEM_BYTES <= 160 * 1024, "LDS over 160 KiB");
  static_assert(SMEM_BYTES == 134336, "unexpected LDS size");
  (void)hipFuncSetAttribute(reinterpret_cast<const void*>(&gru_rec),
                            hipFuncAttributeMaxDynamicSharedMemorySize, SMEM_BYTES);
  gru_rec<<<RG, 256, SMEM_BYTES, stream>>>(whiE, wloE, whiD, wloD, b_hh_enc, b_hh_dec,
                                           gie, gid, Hpk, flags, Hall);

  // logits = h2 @ fc_W^T + fc_b  (M=2048 pad, N=32000, K=512)
  gemm_bt<NH, 1><<<4000, 256, 0, stream>>>(Hall, fcWbf, fc_b, out, 2016, 0);
}